// Round 7
// baseline (259.332 us; speedup 1.0000x reference)
//
#include <hip/hip_runtime.h>

typedef _Float16 h8 __attribute__((ext_vector_type(8)));
typedef _Float16 h2 __attribute__((ext_vector_type(2)));
typedef float f4 __attribute__((ext_vector_type(4)));

#define NHEADS 6
#define LOGMAX 4.6051701859880914f   // ln(100)

// kept position j (0..31) -> row index in window (0..63); kept iff (r+c) even
__device__ __forceinline__ int S_of(int j) { return ((j >> 2) << 3) + ((j & 3) << 1) + ((j >> 2) & 1); }
// complement (masked) position
__device__ __forceinline__ int SC_of(int j) { return ((j >> 2) << 3) + ((j & 3) << 1) + (1 - ((j >> 2) & 1)); }

// 16-lane (DPP row) reductions on the VALU pipe — replaces ds_swizzle shuffles.
template <int CTRL>
__device__ __forceinline__ float dpp_mov(float x) {
    return __builtin_bit_cast(float,
        __builtin_amdgcn_update_dpp(0, __builtin_bit_cast(int, x), CTRL, 0xF, 0xF, true));
}
__device__ __forceinline__ float rowsum16(float x) {
    x += dpp_mov<0x121>(x);   // row_ror:1
    x += dpp_mov<0x122>(x);   // row_ror:2
    x += dpp_mov<0x124>(x);   // row_ror:4
    x += dpp_mov<0x128>(x);   // row_ror:8
    return x;
}
__device__ __forceinline__ float rowmax16(float x) {
    x = fmaxf(x, dpp_mov<0x121>(x));
    x = fmaxf(x, dpp_mov<0x122>(x));
    x = fmaxf(x, dpp_mov<0x124>(x));
    x = fmaxf(x, dpp_mov<0x128>(x));
    return x;
}
__device__ __forceinline__ unsigned pack2(float a, float b) {
    h2 v; v[0] = (_Float16)a; v[1] = (_Float16)b;   // RTE casts + v_pack
    return __builtin_bit_cast(unsigned, v);
}

// ---------------------------------------------------------------------------
// Pack kernel.
// qkvp: [h][nt 0..5][ks 0..5][lane][8]   (k-dim = input feature, natural order)
//   nt: 0,1=q cols 0:16/16:32 ; 2,3=k ; 4,5=v
//   elem = qkv_w[(nt>>1)*192 + h*32 + (nt&1)*16 + (l&15)][ks*32 + (l>>4)*8 + j]
// projp: [ksblk=h 0..5][nt 0..11][lane][8], k-dim PAIR-INTERLEAVED within each
//   32-feature block: pi-pos p <-> feature h*32 + (p>>1) + ((p&1)<<4)
// biask: [h][32][32] = rel_bias_table[rel_pos_index[S(row)][S(col)]][h]
// ---------------------------------------------------------------------------
__global__ void pack_kernel(const float* __restrict__ qkv_w,
                            const float* __restrict__ proj_w,
                            const float* __restrict__ rel_bias_table,
                            const int* __restrict__ rel_pos_index,
                            _Float16* __restrict__ qkvp,
                            _Float16* __restrict__ projp,
                            float* __restrict__ biask) {
    int tid = blockIdx.x * 256 + threadIdx.x;
    const int NQ = 6 * 6 * 6 * 64;        // 13824
    const int NP = 6 * 12 * 64;           // 4608
    if (tid < NQ) {
        int l = tid & 63;
        int rest = tid >> 6;
        int ks = rest % 6;
        int nt = (rest / 6) % 6;
        int h = rest / 36;
        int o = (nt >> 1) * 192 + h * 32 + (nt & 1) * 16 + (l & 15);
        int k0 = ks * 32 + (l >> 4) * 8;
        const float* src = qkv_w + o * 192 + k0;
        _Float16* dst = qkvp + tid * 8;
#pragma unroll
        for (int j = 0; j < 8; ++j) dst[j] = (_Float16)src[j];
    } else if (tid < NQ + NP) {
        int t = tid - NQ;
        int l = t & 63;
        int rest = t >> 6;         // 0..71
        int nt = rest % 12;
        int h = rest / 12;         // k-block (head)
        int o = nt * 16 + (l & 15);
        const float* srcrow = proj_w + o * 192 + h * 32;
        _Float16* dst = projp + t * 8;
        int p0 = (l >> 4) * 8;
#pragma unroll
        for (int j = 0; j < 8; ++j) {
            int p = p0 + j;
            dst[j] = (_Float16)srcrow[(p >> 1) + ((p & 1) << 4)];
        }
    } else if (tid < NQ + NP + 6 * 32 * 32) {
        int t = tid - (NQ + NP);
        int h = t >> 10;
        int jr = (t >> 5) & 31;
        int ic = t & 31;
        int rp = rel_pos_index[S_of(jr) * 64 + S_of(ic)];
        biask[t] = rel_bias_table[rp * NHEADS + h];
    }
}

// ---------------------------------------------------------------------------
// Main fused kernel: 1 block = ONE window, 2 waves (128 threads); wave mh owns
// 16 rows. 19200 B LDS -> 8 blocks/CU: same 16 waves/CU as round 6 but 2x the
// independent serial chains and barriers that sync only 2 waves (round-6
// counters: nothing >42% busy => latency-bound on too-few streams).
// DPP reductions on VALU; pair-interleaved packed-b32 LDS writes.
// ---------------------------------------------------------------------------
__global__ __launch_bounds__(128) __attribute__((amdgpu_waves_per_eu(4, 8)))
void cwa_kernel(
    const float* __restrict__ x,
    const _Float16* __restrict__ qkvp,
    const _Float16* __restrict__ projp,
    const float* __restrict__ biask,
    const float* __restrict__ qkv_b,
    const float* __restrict__ proj_b,
    const float* __restrict__ logit_scale,
    float* __restrict__ out) {
    __shared__ __align__(16) unsigned knu[32][20];   // [kv][d-pair]  2560 B
    __shared__ __align__(16) _Float16 vT[32][40];    // [d][kv-pi]    2560 B
    __shared__ __align__(16) unsigned tmpu[2][16][20]; // wave-priv q/p 2560 B
    __shared__ __align__(16) unsigned outSu[32][100];  // [row][f-pair] 12800 B
    // total 19200 B (+granularity) -> 8 blocks/CU

    const int tid = threadIdx.x;
    const int lane = tid & 63;
    const int mh = tid >> 6;    // wave = 16-row m-half of the window
    const int cl = lane & 15;
    const int g = lane >> 4;
    const long w0 = blockIdx.x;  // one window per block

    // ---- masked rows: output = proj_b ----
    {
        int rowi = tid >> 2;   // 0..31 masked rows
        int sub = tid & 3;
        long base = (w0 * 64 + SC_of(rowi)) * 192;
#pragma unroll
        for (int i = 0; i < 12; ++i) {
            int c4 = i * 4 + sub;
            *(f4*)(out + base + c4 * 4) = *(const f4*)(proj_b + c4 * 4);
        }
    }

    // ---- load this wave's 16 x-rows into A-fragment registers (fp16) ----
    h8 xf[6];
    {
        long xbase = (w0 * 64 + S_of(mh * 16 + cl)) * 192;
#pragma unroll
        for (int ks = 0; ks < 6; ++ks) {
            f4 u0 = *(const f4*)(x + xbase + ks * 32 + g * 8);
            f4 u1 = *(const f4*)(x + xbase + ks * 32 + g * 8 + 4);
            h8 hv;
            hv[0] = (_Float16)u0[0]; hv[1] = (_Float16)u0[1];
            hv[2] = (_Float16)u0[2]; hv[3] = (_Float16)u0[3];
            hv[4] = (_Float16)u1[0]; hv[5] = (_Float16)u1[1];
            hv[6] = (_Float16)u1[2]; hv[7] = (_Float16)u1[3];
            xf[ks] = hv;
        }
    }

#pragma unroll 1
    for (int h = 0; h < NHEADS; ++h) {
        const _Float16* qb_h = qkvp + (long)h * 6 * 6 * 64 * 8;

        // ================= Phase A: qkv GEMM (6 accumulators) ===============
        f4 acc[6];
#pragma unroll
        for (int nt = 0; nt < 6; ++nt) acc[nt] = 0.0f;
#pragma unroll
        for (int ks = 0; ks < 6; ++ks) {
#pragma unroll
            for (int nt = 0; nt < 6; ++nt) {
                h8 b = *(const h8*)(qb_h + (((nt * 6 + ks) * 64 + lane) << 3));
                acc[nt] = __builtin_amdgcn_mfma_f32_16x16x32_f16(xf[ks], b, acc[nt], 0, 0, 0);
            }
        }
        // ---- epilogue compute (registers only, DPP reductions) ----
        float bq0 = qkv_b[h * 32 + cl], bq1 = qkv_b[h * 32 + 16 + cl];
        float bk0 = qkv_b[192 + h * 32 + cl], bk1 = qkv_b[192 + h * 32 + 16 + cl];
        float bv0 = qkv_b[384 + h * 32 + cl], bv1 = qkv_b[384 + h * 32 + 16 + cl];
        unsigned qw[4], kw[4];
        float vv0[4], vv1[4];
#pragma unroll
        for (int r = 0; r < 4; ++r) {
            float t0 = acc[0][r] + bq0, t1 = acc[1][r] + bq1;
            float ss = rowsum16(t0 * t0 + t1 * t1);
            float rs = 1.0f / fmaxf(sqrtf(ss), 1e-12f);
            qw[r] = pack2(t0 * rs, t1 * rs);
            t0 = acc[2][r] + bk0; t1 = acc[3][r] + bk1;
            ss = rowsum16(t0 * t0 + t1 * t1);
            rs = 1.0f / fmaxf(sqrtf(ss), 1e-12f);
            kw[r] = pack2(t0 * rs, t1 * rs);
            vv0[r] = acc[4][r] + bv0;
            vv1[r] = acc[5][r] + bv1;
        }
        __syncthreads();   // both waves done READING kn/vT of head h-1
#pragma unroll
        for (int r = 0; r < 4; ++r) {
            int q = g * 4 + r;            // row within this wave's 16
            tmpu[mh][q][cl] = qw[r];
            knu[mh * 16 + q][cl] = kw[r];
            int kvpos = 2 * q + mh;       // kv pair-interleave position
            vT[cl][kvpos] = (_Float16)vv0[r];
            vT[16 + cl][kvpos] = (_Float16)vv1[r];
        }
        __syncthreads();   // kn/vT ready for phase B

        // ================= Phase B: attention (own 16 q-rows) ===============
        {
            h8 aq = *(const h8*)(&tmpu[mh][cl][g * 4]);
            f4 sN[2];
            sN[0] = 0.0f; sN[1] = 0.0f;
#pragma unroll
            for (int nt = 0; nt < 2; ++nt) {
                h8 bk_ = *(const h8*)(&knu[nt * 16 + cl][g * 4]);
                sN[nt] = __builtin_amdgcn_mfma_f32_16x16x32_f16(aq, bk_, sN[nt], 0, 0, 0);
            }
            float scale = __expf(fminf(logit_scale[h], LOGMAX));
            float lg[2][4];
#pragma unroll
            for (int nt = 0; nt < 2; ++nt)
#pragma unroll
                for (int r = 0; r < 4; ++r)
                    lg[nt][r] = sN[nt][r] * scale +
                                biask[h * 1024 + (mh * 16 + g * 4 + r) * 32 + nt * 16 + cl];
            unsigned pw[4];
#pragma unroll
            for (int r = 0; r < 4; ++r) {
                float mx = rowmax16(fmaxf(lg[0][r], lg[1][r]));
                float e0 = __expf(lg[0][r] - mx);
                float e1 = __expf(lg[1][r] - mx);
                float inv = 1.0f / rowsum16(e0 + e1);
                pw[r] = pack2(e0 * inv, e1 * inv);
            }
#pragma unroll
            for (int r = 0; r < 4; ++r)
                tmpu[mh][g * 4 + r][cl] = pw[r];
            h8 ap = *(const h8*)(&tmpu[mh][cl][g * 4]);
            f4 ov[2];
            ov[0] = 0.0f; ov[1] = 0.0f;
#pragma unroll
            for (int nt = 0; nt < 2; ++nt) {
                h8 bv_ = *(const h8*)(&vT[nt * 16 + cl][g * 8]);
                ov[nt] = __builtin_amdgcn_mfma_f32_16x16x32_f16(ap, bv_, ov[nt], 0, 0, 0);
            }
            // packed O write: pair (col, col+16) within this head's 32 f-cols
#pragma unroll
            for (int r = 0; r < 4; ++r)
                outSu[mh * 16 + g * 4 + r][h * 16 + cl] = pack2(ov[0][r], ov[1][r]);
        }
        // next head's A-GEMM touches no shared LDS; its bar1 orders kn/vT reuse
    }
    __syncthreads();   // outSu complete

    // ======== Phase C: proj GEMM, 2 passes of 3 n-tiles (reg-peak cap) ======
    {
        const int wn = mh;          // 96-col half
        const int r0 = cl;
        const int r1 = 16 + cl;
#pragma unroll 1
        for (int pass = 0; pass < 2; ++pass) {
            f4 pa0[3], pa1[3];
#pragma unroll
            for (int nt = 0; nt < 3; ++nt) { pa0[nt] = 0.0f; pa1[nt] = 0.0f; }
#pragma unroll
            for (int ks = 0; ks < 6; ++ks) {
                h8 a0 = *(const h8*)(&outSu[r0][ks * 16 + g * 4]);
                h8 a1 = *(const h8*)(&outSu[r1][ks * 16 + g * 4]);
#pragma unroll
                for (int nt = 0; nt < 3; ++nt) {
                    int ntg = wn * 6 + pass * 3 + nt;
                    h8 b = *(const h8*)(projp + (((ks * 12 + ntg) * 64 + lane) << 3));
                    pa0[nt] = __builtin_amdgcn_mfma_f32_16x16x32_f16(a0, b, pa0[nt], 0, 0, 0);
                    pa1[nt] = __builtin_amdgcn_mfma_f32_16x16x32_f16(a1, b, pa1[nt], 0, 0, 0);
                }
            }
#pragma unroll
            for (int m = 0; m < 2; ++m) {
                const f4* pm = m ? pa1 : pa0;
#pragma unroll
                for (int r = 0; r < 4; ++r) {
                    int rl = m * 16 + g * 4 + r;   // local row in window
                    long grow = w0 * 64 + S_of(rl);
                    float* po_ = out + grow * 192 + wn * 96 + pass * 48 + cl;
#pragma unroll
                    for (int nt = 0; nt < 3; ++nt)
                        po_[nt * 16] = pm[nt][r] + proj_b[wn * 96 + pass * 48 + nt * 16 + cl];
                }
            }
        }
    }
}

extern "C" void kernel_launch(void* const* d_in, const int* in_sizes, int n_in,
                              void* d_out, int out_size, void* d_ws, size_t ws_size,
                              hipStream_t stream) {
    const float* x = (const float*)d_in[0];
    const float* qkv_w = (const float*)d_in[1];
    const float* qkv_b = (const float*)d_in[2];
    const float* proj_w = (const float*)d_in[3];
    const float* proj_b = (const float*)d_in[4];
    const float* logit_scale = (const float*)d_in[5];
    const float* rel_bias_table = (const float*)d_in[6];
    const int* rel_pos_index = (const int*)d_in[7];
    float* out = (float*)d_out;

    const int B = in_sizes[0] / (64 * 192);   // number of windows (8192)

    _Float16* qkvp = (_Float16*)d_ws;                 // 13824*8 f16
    _Float16* projp = qkvp + 6 * 6 * 6 * 64 * 8;      // 4608*8 f16
    float* biask = (float*)(projp + 6 * 12 * 64 * 8); // 6*32*32 f32

    pack_kernel<<<96, 256, 0, stream>>>(qkv_w, proj_w, rel_bias_table, rel_pos_index,
                                        qkvp, projp, biask);
    cwa_kernel<<<B, 128, 0, stream>>>(x, qkvp, projp, biask, qkv_b, proj_b,
                                      logit_scale, out);
}

// Round 8
// 239.821 us; speedup vs baseline: 1.0814x; 1.0814x over previous
//
#include <hip/hip_runtime.h>

typedef _Float16 h8 __attribute__((ext_vector_type(8)));
typedef _Float16 h2 __attribute__((ext_vector_type(2)));
typedef float f4 __attribute__((ext_vector_type(4)));

#define NHEADS 6
#define LOGMAX 4.6051701859880914f   // ln(100)

// kept position j (0..31) -> row index in window (0..63); kept iff (r+c) even
__device__ __forceinline__ int S_of(int j) { return ((j >> 2) << 3) + ((j & 3) << 1) + ((j >> 2) & 1); }
// complement (masked) position
__device__ __forceinline__ int SC_of(int j) { return ((j >> 2) << 3) + ((j & 3) << 1) + (1 - ((j >> 2) & 1)); }

// 16-lane (DPP row) reductions on the VALU pipe.
template <int CTRL>
__device__ __forceinline__ float dpp_mov(float x) {
    return __builtin_bit_cast(float,
        __builtin_amdgcn_update_dpp(0, __builtin_bit_cast(int, x), CTRL, 0xF, 0xF, true));
}
__device__ __forceinline__ float rowsum16(float x) {
    x += dpp_mov<0x121>(x);   // row_ror:1
    x += dpp_mov<0x122>(x);   // row_ror:2
    x += dpp_mov<0x124>(x);   // row_ror:4
    x += dpp_mov<0x128>(x);   // row_ror:8
    return x;
}
__device__ __forceinline__ float rowmax16(float x) {
    x = fmaxf(x, dpp_mov<0x121>(x));
    x = fmaxf(x, dpp_mov<0x122>(x));
    x = fmaxf(x, dpp_mov<0x124>(x));
    x = fmaxf(x, dpp_mov<0x128>(x));
    return x;
}
__device__ __forceinline__ unsigned pack2(float a, float b) {
    h2 v; v[0] = (_Float16)a; v[1] = (_Float16)b;
    return __builtin_bit_cast(unsigned, v);
}

// ---------------------------------------------------------------------------
// Pack kernel (unchanged layouts from round 6/7).
// qkvp: [h][nt 0..5][ks 0..5][lane][8]
// projp: [ksblk=h][nt 0..11][lane][8], k-dim pair-interleaved within head block
// biask: [h][32][32]
// ---------------------------------------------------------------------------
__global__ void pack_kernel(const float* __restrict__ qkv_w,
                            const float* __restrict__ proj_w,
                            const float* __restrict__ rel_bias_table,
                            const int* __restrict__ rel_pos_index,
                            _Float16* __restrict__ qkvp,
                            _Float16* __restrict__ projp,
                            float* __restrict__ biask) {
    int tid = blockIdx.x * 256 + threadIdx.x;
    const int NQ = 6 * 6 * 6 * 64;        // 13824
    const int NP = 6 * 12 * 64;           // 4608
    if (tid < NQ) {
        int l = tid & 63;
        int rest = tid >> 6;
        int ks = rest % 6;
        int nt = (rest / 6) % 6;
        int h = rest / 36;
        int o = (nt >> 1) * 192 + h * 32 + (nt & 1) * 16 + (l & 15);
        int k0 = ks * 32 + (l >> 4) * 8;
        const float* src = qkv_w + o * 192 + k0;
        _Float16* dst = qkvp + tid * 8;
#pragma unroll
        for (int j = 0; j < 8; ++j) dst[j] = (_Float16)src[j];
    } else if (tid < NQ + NP) {
        int t = tid - NQ;
        int l = t & 63;
        int rest = t >> 6;         // 0..71
        int nt = rest % 12;
        int h = rest / 12;         // k-block (head)
        int o = nt * 16 + (l & 15);
        const float* srcrow = proj_w + o * 192 + h * 32;
        _Float16* dst = projp + t * 8;
        int p0 = (l >> 4) * 8;
#pragma unroll
        for (int j = 0; j < 8; ++j) {
            int p = p0 + j;
            dst[j] = (_Float16)srcrow[(p >> 1) + ((p & 1) << 4)];
        }
    } else if (tid < NQ + NP + 6 * 32 * 32) {
        int t = tid - (NQ + NP);
        int h = t >> 10;
        int jr = (t >> 5) & 31;
        int ic = t & 31;
        int rp = rel_pos_index[S_of(jr) * 64 + S_of(ic)];
        biask[t] = rel_bias_table[rp * NHEADS + h];
    }
}

// ---------------------------------------------------------------------------
// Main fused kernel: 256 thr = 4 waves = 2 windows; wave (w,mh) owns 16 rows.
// Per head, the 36 KB qkv weight tile is DMA'd into LDS (global_load_lds) by
// all 4 waves, issued right after the previous A-GEMM's ds_reads finish and
// kept in flight across epilogue+phaseB (raw s_barrier + lgkm-only waits).
// A-GEMM B-frags then come from LDS (~12cyc) instead of per-wave L2 (~200cyc)
// — rounds 6/7 showed no pipe >42% busy: L2-latency-bound on weight streams.
// Proj accumulated incrementally in pacc[12] (3-waves/EU reg tier, no outS).
// ---------------------------------------------------------------------------
__global__ __launch_bounds__(256) __attribute__((amdgpu_waves_per_eu(3, 8)))
void cwa_kernel(
    const float* __restrict__ x,
    const _Float16* __restrict__ qkvp,
    const _Float16* __restrict__ projp,
    const float* __restrict__ biask,
    const float* __restrict__ qkv_b,
    const float* __restrict__ proj_b,
    const float* __restrict__ logit_scale,
    float* __restrict__ out) {
    __shared__ __align__(16) _Float16 wbuf[6 * 6 * 64 * 8];   // 36864 B head tile
    __shared__ __align__(16) unsigned knu[2][32][20];         // 5120 B
    __shared__ __align__(16) _Float16 vT[2][32][40];          // 5120 B
    __shared__ __align__(16) unsigned tmpu[4][16][20];        // 5120 B (q/p/O)
    // total 52224 B -> 3 blocks/CU (12 waves)

    const int tid = threadIdx.x;
    const int lane = tid & 63;
    const int wave = tid >> 6;
    const int cl = lane & 15;
    const int g = lane >> 4;
    const int w0 = blockIdx.x * 2;
    const int w = wave >> 1;    // window within block
    const int mh = wave & 1;    // 16-row m-half within window

    // ---- async-stage head h's weight tile: 9 chunks of 1 KB per wave ----
    auto stage = [&](int h) {
        const _Float16* srcb = qkvp + (long)h * (6 * 6 * 64 * 8) + (wave * 9) * 512 + lane * 8;
        _Float16* dstb = &wbuf[(wave * 9) * 512];
#pragma unroll
        for (int c = 0; c < 9; ++c)
            __builtin_amdgcn_global_load_lds(
                (const __attribute__((address_space(1))) unsigned*)(srcb + c * 512),
                (__attribute__((address_space(3))) unsigned*)(dstb + c * 512),
                16, 0, 0);
    };

    stage(0);   // DMA flies under the prologue below

    // ---- masked rows: output = proj_b ----
    {
        int rowi = tid >> 2;   // 0..63  (2 windows x 32 masked rows)
        int sub = tid & 3;
        long base = ((long)(w0 + (rowi >> 5)) * 64 + SC_of(rowi & 31)) * 192;
#pragma unroll
        for (int i = 0; i < 12; ++i) {
            int c4 = i * 4 + sub;
            *(f4*)(out + base + c4 * 4) = *(const f4*)(proj_b + c4 * 4);
        }
    }

    // ---- load this wave's 16 x-rows into A-fragment registers (fp16) ----
    h8 xf[6];
    {
        long xbase = ((long)(w0 + w) * 64 + S_of(mh * 16 + cl)) * 192;
#pragma unroll
        for (int ks = 0; ks < 6; ++ks) {
            f4 u0 = *(const f4*)(x + xbase + ks * 32 + g * 8);
            f4 u1 = *(const f4*)(x + xbase + ks * 32 + g * 8 + 4);
            h8 hv;
            hv[0] = (_Float16)u0[0]; hv[1] = (_Float16)u0[1];
            hv[2] = (_Float16)u0[2]; hv[3] = (_Float16)u0[3];
            hv[4] = (_Float16)u1[0]; hv[5] = (_Float16)u1[1];
            hv[6] = (_Float16)u1[2]; hv[7] = (_Float16)u1[3];
            xf[ks] = hv;
        }
    }

    f4 pacc[12];
#pragma unroll
    for (int nt = 0; nt < 12; ++nt) pacc[nt] = 0.0f;

#pragma unroll 1
    for (int h = 0; h < NHEADS; ++h) {
        // ---- barrier alpha: everyone's stage DMA for head h has landed ----
        asm volatile("s_waitcnt vmcnt(0)" ::: "memory");
        __builtin_amdgcn_s_barrier();

        // ================= Phase A: qkv GEMM from LDS wbuf ==================
        f4 acc[6];
#pragma unroll
        for (int nt = 0; nt < 6; ++nt) acc[nt] = 0.0f;
#pragma unroll
        for (int ks = 0; ks < 6; ++ks) {
#pragma unroll
            for (int nt = 0; nt < 6; ++nt) {
                h8 b = *(const h8*)(&wbuf[((nt * 6 + ks) * 64 + lane) * 8]);
                acc[nt] = __builtin_amdgcn_mfma_f32_16x16x32_f16(xf[ks], b, acc[nt], 0, 0, 0);
            }
        }
        // ---- barrier beta: all waves done reading wbuf -> safe to overwrite
        asm volatile("s_waitcnt lgkmcnt(0)" ::: "memory");
        __builtin_amdgcn_s_barrier();
        if (h + 1 < NHEADS) stage(h + 1);   // DMA overlaps epilogue + phase B

        // ---- epilogue (registers only, DPP reductions) ----
        float bq0 = qkv_b[h * 32 + cl], bq1 = qkv_b[h * 32 + 16 + cl];
        float bk0 = qkv_b[192 + h * 32 + cl], bk1 = qkv_b[192 + h * 32 + 16 + cl];
        float bv0 = qkv_b[384 + h * 32 + cl], bv1 = qkv_b[384 + h * 32 + 16 + cl];
        unsigned qw[4], kw[4];
        float vv0[4], vv1[4];
#pragma unroll
        for (int r = 0; r < 4; ++r) {
            float t0 = acc[0][r] + bq0, t1 = acc[1][r] + bq1;
            float ss = rowsum16(t0 * t0 + t1 * t1);
            float rs = 1.0f / fmaxf(sqrtf(ss), 1e-12f);
            qw[r] = pack2(t0 * rs, t1 * rs);
            t0 = acc[2][r] + bk0; t1 = acc[3][r] + bk1;
            ss = rowsum16(t0 * t0 + t1 * t1);
            rs = 1.0f / fmaxf(sqrtf(ss), 1e-12f);
            kw[r] = pack2(t0 * rs, t1 * rs);
            vv0[r] = acc[4][r] + bv0;
            vv1[r] = acc[5][r] + bv1;
        }
#pragma unroll
        for (int r = 0; r < 4; ++r) {
            int q = g * 4 + r;
            tmpu[wave][q][cl] = qw[r];
            knu[w][mh * 16 + q][cl] = kw[r];
            int kvpos = 2 * q + mh;
            vT[w][cl][kvpos] = (_Float16)vv0[r];
            vT[w][16 + cl][kvpos] = (_Float16)vv1[r];
        }
        // ---- barrier gamma: kn/vT visible; vmcnt NOT drained (DMA in flight)
        asm volatile("s_waitcnt lgkmcnt(0)" ::: "memory");
        __builtin_amdgcn_s_barrier();

        // ================= Phase B: attention + incremental proj ============
        {
            h8 aq = *(const h8*)(&tmpu[wave][cl][g * 4]);
            f4 sN[2];
            sN[0] = 0.0f; sN[1] = 0.0f;
#pragma unroll
            for (int nt = 0; nt < 2; ++nt) {
                h8 bk_ = *(const h8*)(&knu[w][nt * 16 + cl][g * 4]);
                sN[nt] = __builtin_amdgcn_mfma_f32_16x16x32_f16(aq, bk_, sN[nt], 0, 0, 0);
            }
            float scale = __expf(fminf(logit_scale[h], LOGMAX));
            float lg[2][4];
#pragma unroll
            for (int nt = 0; nt < 2; ++nt)
#pragma unroll
                for (int r = 0; r < 4; ++r)
                    lg[nt][r] = sN[nt][r] * scale +
                                biask[h * 1024 + (mh * 16 + g * 4 + r) * 32 + nt * 16 + cl];
            unsigned pw[4];
#pragma unroll
            for (int r = 0; r < 4; ++r) {
                float mx = rowmax16(fmaxf(lg[0][r], lg[1][r]));
                float e0 = __expf(lg[0][r] - mx);
                float e1 = __expf(lg[1][r] - mx);
                float inv = 1.0f / rowsum16(e0 + e1);
                pw[r] = pack2(e0 * inv, e1 * inv);
            }
#pragma unroll
            for (int r = 0; r < 4; ++r)
                tmpu[wave][g * 4 + r][cl] = pw[r];
            h8 ap = *(const h8*)(&tmpu[wave][cl][g * 4]);
            f4 ov[2];
            ov[0] = 0.0f; ov[1] = 0.0f;
#pragma unroll
            for (int nt = 0; nt < 2; ++nt) {
                h8 bv_ = *(const h8*)(&vT[w][nt * 16 + cl][g * 8]);
                ov[nt] = __builtin_amdgcn_mfma_f32_16x16x32_f16(ap, bv_, ov[nt], 0, 0, 0);
            }
            // O_h -> tmpu (pair-packed, wave-private), then incremental proj
#pragma unroll
            for (int r = 0; r < 4; ++r)
                tmpu[wave][g * 4 + r][cl] = pack2(ov[0][r], ov[1][r]);
            h8 am = *(const h8*)(&tmpu[wave][cl][g * 4]);
            const _Float16* pp_h = projp + (long)h * 12 * 64 * 8;
#pragma unroll
            for (int nt = 0; nt < 12; ++nt) {
                h8 bp = *(const h8*)(pp_h + ((nt * 64 + lane) << 3));
                pacc[nt] = __builtin_amdgcn_mfma_f32_16x16x32_f16(am, bp, pacc[nt], 0, 0, 0);
            }
        }
        // loop: next alpha drains vmcnt (stage h+1) before touching wbuf
    }

    // ================= Final store: out = pacc + proj_b =================
#pragma unroll
    for (int r = 0; r < 4; ++r) {
        long grow = (long)(w0 + w) * 64 + S_of(mh * 16 + g * 4 + r);
        float* po_ = out + grow * 192 + cl;
#pragma unroll
        for (int nt = 0; nt < 12; ++nt)
            po_[nt * 16] = pacc[nt][r] + proj_b[nt * 16 + cl];
    }
}

extern "C" void kernel_launch(void* const* d_in, const int* in_sizes, int n_in,
                              void* d_out, int out_size, void* d_ws, size_t ws_size,
                              hipStream_t stream) {
    const float* x = (const float*)d_in[0];
    const float* qkv_w = (const float*)d_in[1];
    const float* qkv_b = (const float*)d_in[2];
    const float* proj_w = (const float*)d_in[3];
    const float* proj_b = (const float*)d_in[4];
    const float* logit_scale = (const float*)d_in[5];
    const float* rel_bias_table = (const float*)d_in[6];
    const int* rel_pos_index = (const int*)d_in[7];
    float* out = (float*)d_out;

    const int B = in_sizes[0] / (64 * 192);   // number of windows (8192)

    _Float16* qkvp = (_Float16*)d_ws;                 // 13824*8 f16
    _Float16* projp = qkvp + 6 * 6 * 6 * 64 * 8;      // 4608*8 f16
    float* biask = (float*)(projp + 6 * 12 * 64 * 8); // 6*32*32 f32

    pack_kernel<<<96, 256, 0, stream>>>(qkv_w, proj_w, rel_bias_table, rel_pos_index,
                                        qkvp, projp, biask);
    cwa_kernel<<<B / 2, 256, 0, stream>>>(x, qkvp, projp, biask, qkv_b, proj_b,
                                          logit_scale, out);
}